// Round 10
// baseline (1022.785 us; speedup 1.0000x reference)
//
#include <hip/hip_runtime.h>
#include <hip/hip_bf16.h>

typedef _Float16 half8 __attribute__((ext_vector_type(8)));
typedef float f32x4 __attribute__((ext_vector_type(4)));

constexpr float L2E   = 1.44269504088896340736f;
constexpr float SC_LO = 4096.0f;        // 2^12, exact
constexpr float IV_LO = 1.0f / 4096.0f; // 2^-12, exact

#define MFMA16(a,b,c) __builtin_amdgcn_mfma_f32_16x16x32_f16((a),(b),(c),0,0,0)

__device__ __forceinline__ float fexp2(float x){ float r; asm("v_exp_f32 %0, %1":"=v"(r):"v"(x)); return r; }
__device__ __forceinline__ float frcp(float x){ float r; asm("v_rcp_f32 %0, %1":"=v"(r):"v"(x)); return r; }

// sigmoid(x) where y = L2E*x was pre-scaled into weights
__device__ __forceinline__ float sigm_s(float y){ return frcp(1.0f + fexp2(-y)); }
// tanh(x) where y = 2*L2E*x was pre-scaled into weights
__device__ __forceinline__ float tanh_s(float y){ return 1.0f - 2.0f*frcp(fexp2(y) + 1.0f); }

// ---------------------------------------------------------------------------
// Shared encoder LSTM. Split precision ONLY on the recurrent path (whh hi+lo,
// h hi+lo) — R6/R7 showed those are the accuracy-critical corrections; the
// input path (emb, Wih) runs hi-only, freeing ~24 regs + 32 MFMAs/step so
// that 3 waves/SIMD fit WITHOUT spilling (R8: forcing 3 at full demand
// spilled, FETCH 8.7MB->3.3GB; watch FETCH_SIZE).
// MERGED dispatch: blocks [0,64) = hist, [64,2112) = nbrs.
// Ping-pong h buffers: one barrier per step.
// ---------------------------------------------------------------------------
__global__ __launch_bounds__(256, 3)
void lstm_enc_kernel(const float* __restrict__ xh,     // hist [16][4096][2]
                     const float* __restrict__ xn,     // nbrs [16][131072][2]
                     const float* __restrict__ W_inp,  // [32][2]
                     const float* __restrict__ b_inp,  // [32]
                     const float* __restrict__ Wih,    // [256][32]
                     const float* __restrict__ Whh,    // [256][64]
                     const float* __restrict__ bih,    // [256]
                     const float* __restrict__ bhh,    // [256]
                     float* __restrict__ outh,         // [4096][64] fp32
                     float* __restrict__ outn)         // [131072][64] fp32
{
    __shared__ _Float16 h_hi[2][64*72];   // 72-pad; ping-pong
    __shared__ _Float16 h_ls[2][64*72];   // lo * 4096
    const int tid = threadIdx.x;
    const int w   = tid >> 6;
    const int l   = tid & 63;
    const int l15 = l & 15, lhi = l >> 4;

    const int bid = blockIdx.x;
    const bool is_hist = (bid < 64);
    const float* x = is_hist ? xh : xn;
    float* out     = is_hist ? outh : outn;
    const int N    = is_hist ? 4096 : 131072;
    const int rbase = (is_hist ? bid : (bid - 64)) * 64;

    // resident B-fragments: recurrent split (hi + 2^12*lo), input hi-only
    half8 whhH[4][2], whhLs[4][2];  // [gate][khalf]
    half8 wihH[4];
    float bias[4];
#pragma unroll
    for (int g = 0; g < 4; ++g) {
        const int col = 16*(w + 4*g) + l15;           // global gate column
        const float sc = (g == 2) ? 2.0f*L2E : L2E;
#pragma unroll
        for (int kh = 0; kh < 2; ++kh)
#pragma unroll
            for (int j = 0; j < 8; ++j) {
                const float v = Whh[col*64 + kh*32 + lhi*8 + j] * sc;
                const _Float16 hi = (_Float16)v;
                whhH[g][kh][j]  = hi;
                whhLs[g][kh][j] = (_Float16)((v - (float)hi) * SC_LO);
            }
#pragma unroll
        for (int j = 0; j < 8; ++j)
            wihH[g][j] = (_Float16)(Wih[col*32 + lhi*8 + j] * sc);
        bias[g] = (bih[col] + bhh[col]) * sc;
    }
    // W_inp columns for this lane's emb A-frag slots (k = lhi*8 + j)
    float w0[8], w1[8], bb[8];
#pragma unroll
    for (int j = 0; j < 8; ++j) {
        const int k = lhi*8 + j;
        w0[j] = W_inp[k*2 + 0]; w1[j] = W_inp[k*2 + 1]; bb[j] = b_inp[k];
    }

    float c[4][4];   // cell state: (row = 16m + lhi*4 + j, e = 16w + l15)
#pragma unroll
    for (int m = 0; m < 4; ++m)
#pragma unroll
        for (int j = 0; j < 4; ++j) c[m][j] = 0.0f;

    const float2* xp = (const float2*)x;
    float2 xc[4];
#pragma unroll
    for (int m = 0; m < 4; ++m)
        xc[m] = xp[(size_t)0*N + rbase + 16*m + l15];

    for (int t = 0; t < 16; ++t) {
        const int rdb = (t + 1) & 1;   // h(t-1) buffer
        const int wrb = t & 1;         // h(t) buffer
        float hnew[4][4];
#pragma unroll
        for (int m = 0; m < 4; ++m) {
            // emb (hi-only)
            half8 eh;
#pragma unroll
            for (int j = 0; j < 8; ++j) {
                float v = xc[m].x * w0[j] + xc[m].y * w1[j] + bb[j];
                v = fmaxf(v, 0.1f * v);            // leaky relu
                eh[j] = (_Float16)v;
            }
            f32x4 a0[4], a2[4];
#pragma unroll
            for (int g = 0; g < 4; ++g) {
                a0[g] = (f32x4){bias[g], bias[g], bias[g], bias[g]};
                a2[g] = (f32x4){0.f, 0.f, 0.f, 0.f};
            }
#pragma unroll
            for (int g = 0; g < 4; ++g)
                a0[g] = MFMA16(eh, wihH[g], a0[g]);
            if (t > 0) {
#pragma unroll
                for (int kh = 0; kh < 2; ++kh) {
                    const int off = (16*m + l15)*72 + kh*32 + lhi*8;
                    half8 ah = *(const half8*)&h_hi[rdb][off];
                    half8 as = *(const half8*)&h_ls[rdb][off];
#pragma unroll
                    for (int g = 0; g < 4; ++g) {
                        a0[g] = MFMA16(ah, whhH[g][kh],  a0[g]);
                        a2[g] = MFMA16(ah, whhLs[g][kh], a2[g]);
                        a2[g] = MFMA16(as, whhH[g][kh],  a2[g]);
                    }
                }
            }
            // gates for this m-tile
#pragma unroll
            for (int j = 0; j < 4; ++j) {
                const float pi = a0[0][j] + a2[0][j]*IV_LO;
                const float pf = a0[1][j] + a2[1][j]*IV_LO;
                const float pg = a0[2][j] + a2[2][j]*IV_LO;
                const float po = a0[3][j] + a2[3][j]*IV_LO;
                const float si = sigm_s(pi);
                const float sf = sigm_s(pf);
                const float tg = tanh_s(pg);
                const float so = sigm_s(po);
                const float cc = sf * c[m][j] + si * tg;
                c[m][j] = cc;
                hnew[m][j] = so * tanh_s(2.0f*L2E*cc);
            }
        }
        // write h(t) to the OTHER buffer — no pre-barrier needed
#pragma unroll
        for (int m = 0; m < 4; ++m)
#pragma unroll
            for (int j = 0; j < 4; ++j) {
                const int idx = (16*m + lhi*4 + j)*72 + 16*w + l15;
                const float v = hnew[m][j];
                const _Float16 hi = (_Float16)v;
                h_hi[wrb][idx] = hi;
                h_ls[wrb][idx] = (_Float16)((v - (float)hi) * SC_LO);
            }
        __syncthreads();   // h(t) visible; h(t-1) reads were all pre-write
        if (t < 15) {
#pragma unroll
            for (int m = 0; m < 4; ++m)
                xc[m] = xp[(size_t)(t+1)*N + rbase + 16*m + l15];
        }
    }
    // coalesced fp32 output of final h (in buf[15&1]=1): hi + lo*2^-12
    {
        const int row = tid >> 2, c0 = (tid & 3) * 16;
        const size_t g = (size_t)(rbase + row) * 64 + c0;
#pragma unroll
        for (int i = 0; i < 16; ++i) {
            const int idx = row*72 + c0 + i;
            out[g + i] = (float)h_hi[1][idx] + (float)h_ls[1][idx] * IV_LO;
        }
    }
}

// ---------------------------------------------------------------------------
// hist_enc = lrelu(h_hist @ W_dym^T + b_dym) -> enc[:, 0:32]   (fp32)
// ---------------------------------------------------------------------------
__global__ __launch_bounds__(256)
void hist_enc32_kernel(const float* __restrict__ hh,    // [4096][64]
                       const float* __restrict__ W_dym, // [32][64]
                       const float* __restrict__ b_dym, // [32]
                       float* __restrict__ enc)         // [4096][96]
{
    const int idx = blockIdx.x * 256 + threadIdx.x;
    if (idx >= 4096 * 32) return;
    const int b = idx >> 5, s = idx & 31;
    float a = b_dym[s];
    const float* hr = hh + (size_t)b * 64;
    const float* wr = W_dym + (size_t)s * 64;
#pragma unroll
    for (int e = 0; e < 64; ++e) a += hr[e] * wr[e];
    enc[(size_t)b * 96 + s] = fmaxf(a, 0.1f * a);
}

// ---------------------------------------------------------------------------
// W_spT[p][e][s] = W_sp[s][e*169+p]  (fp32)
// ---------------------------------------------------------------------------
__global__ void wsp_prep32_kernel(const float* __restrict__ W_sp, // [64][10816]
                                  float* __restrict__ WspT)       // [169][64][64]
{
    const int idx = blockIdx.x * 256 + threadIdx.x;
    if (idx >= 64 * 10816) return;
    const int s = idx / 10816, cidx = idx % 10816;
    const int e = cidx / 169, p = cidx % 169;
    WspT[((size_t)p * 64 + e) * 64 + s] = W_sp[idx];
}

// ---------------------------------------------------------------------------
// pos[b][k] = (gw*13+gh) of k-th occupied cell (scan order gh*13+gw).
// Mask dtype auto-detected (R3/R4-proven: int32 on this data).
// ---------------------------------------------------------------------------
__global__ void pos_prep_kernel(const void* __restrict__ mask_raw,
                                unsigned char* __restrict__ pos)  // [4096][32]
{
    const int agent = (int)((blockIdx.x * 256 + threadIdx.x) >> 6);
    const int l = threadIdx.x & 63;
    if (agent >= 4096) return;
    if (l < 32) pos[agent*32 + l] = 0;   // no slot left as stale garbage

    const unsigned char* raw = (const unsigned char*)mask_raw;
    const int* mi = (const int*)mask_raw;

    int mism = 0;
#pragma unroll
    for (int ch = 0; ch < 3; ++ch) {
        const int cc = ch*64 + l;
        if (cc < 169) {
            const unsigned char b0 = raw[cc*64], b1 = raw[cc*64 + 1];
            mism |= (b0 != 0 && b1 == 0) ? 1 : 0;
        }
    }
    const bool is_i32 = (__ballot(mism != 0) != 0ull);

    int base = 0;
#pragma unroll
    for (int ch = 0; ch < 3; ++ch) {
        const int cc = ch*64 + l;
        bool occ = false;
        if (cc < 169) {
            const size_t ei = (size_t)agent * 10816 + (size_t)cc * 64;
            occ = is_i32 ? (mi[ei] != 0) : (raw[ei] != 0);
        }
        const unsigned long long bal = __ballot(occ);
        if (occ) {
            const int rank = base + __popcll(bal & ((1ull << l) - 1ull));
            const int gh = cc / 13, gw = cc % 13;
            if (rank < 32)
                pos[agent*32 + rank] = (unsigned char)(gw*13 + gh);
        }
        base += __popcll(bal);
    }
}

// ---------------------------------------------------------------------------
// social[b][s] = lrelu(b_sp[s] + sum_k sum_e nh[b*32+k][e]*WspT[p_k][e][s])
// (fp32) -> enc[:, 32:96]
// ---------------------------------------------------------------------------
__global__ __launch_bounds__(256)
void social32_kernel(const float* __restrict__ nh,    // [131072][64]
                     const float* __restrict__ WspT,  // [169][64][64]
                     const float* __restrict__ b_sp,  // [64]
                     const unsigned char* __restrict__ pos, // [4096][32]
                     float* __restrict__ enc)         // [4096][96]
{
    __shared__ float part[4][64];
    __shared__ unsigned char pl[32];
    const int tid = threadIdx.x, b = blockIdx.x;
    if (tid < 32) {
        const int p = pos[b*32 + tid];
        pl[tid] = (unsigned char)(p > 168 ? 0 : p);
    }
    __syncthreads();
    const int s = tid & 63, kq = tid >> 6;
    float a = 0.f;
    for (int kk = 0; kk < 8; ++kk) {
        const int k = kq*8 + kk;
        const float* nr = nh + ((size_t)b*32 + k) * 64;
        const float* wp = WspT + (size_t)pl[k] * 4096 + s;
#pragma unroll
        for (int e = 0; e < 64; ++e) a += nr[e] * wp[(size_t)e * 64];
    }
    part[kq][s] = a;
    __syncthreads();
    if (tid < 64) {
        const float v = part[0][tid] + part[1][tid] + part[2][tid] + part[3][tid] + b_sp[tid];
        enc[(size_t)b * 96 + 32 + tid] = fmaxf(v, 0.1f * v);
    }
}

// ---------------------------------------------------------------------------
// Decoder LSTM (128 hidden, 16 steps, xg constant over t) + head.
// Scaled split-precision recurrent path; fp32 enc input; fp32 output.
// Block: 512 thr (8 waves), 16 rows.
// ---------------------------------------------------------------------------
__global__ __launch_bounds__(512, 1)
void decoder_kernel(const float* __restrict__ enc,    // [4096][96] fp32
                    const float* __restrict__ dWih,   // [512][96]
                    const float* __restrict__ dWhh,   // [512][128]
                    const float* __restrict__ dbih,   // [512]
                    const float* __restrict__ dbhh,   // [512]
                    const float* __restrict__ W_out,  // [5][128]
                    const float* __restrict__ b_out,  // [5]
                    float* __restrict__ outp)         // [4096][16][5] fp32
{
    __shared__ float enc_lds[16*100];    // stride 100 floats (400B, 16B-aligned)
    __shared__ _Float16 hh_t[16*136];
    __shared__ _Float16 hl_t[16*136];    // lo * 4096
    __shared__ float wout[5*132];
    __shared__ float bout[5];
    __shared__ float part[16][5][4];
    const int tid = threadIdx.x;
    const int w = tid >> 6, l = tid & 63, l15 = l & 15, lhi = l >> 4;
    const int rb = blockIdx.x * 16;

    if (tid < 384) {
        const int row = tid / 24, ch = tid % 24;
        *(float4*)&enc_lds[row*100 + ch*4] = *(const float4*)&enc[(size_t)(rb + row)*96 + ch*4];
    }
    for (int i = tid; i < 640; i += 512) { const int j = i / 128, e = i % 128; wout[j*132 + e] = W_out[i]; }
    if (tid < 5) bout[tid] = b_out[tid];
    __syncthreads();

    half8 whhH[4][4], whhLs[4][4];  // [gate][khalf]
    f32x4 xg0[4], xg2[4];
#pragma unroll
    for (int g = 0; g < 4; ++g) {
        const int col = 16*(8*g + w) + l15;
        const float sc = (g == 2) ? 2.0f*L2E : L2E;
#pragma unroll
        for (int kh = 0; kh < 4; ++kh)
#pragma unroll
            for (int j = 0; j < 8; ++j) {
                const float v = dWhh[col*128 + kh*32 + lhi*8 + j] * sc;
                const _Float16 hi = (_Float16)v;
                whhH[g][kh][j]  = hi;
                whhLs[g][kh][j] = (_Float16)((v - (float)hi) * SC_LO);
            }
        const float bv = (dbih[col] + dbhh[col]) * sc;
        xg0[g] = (f32x4){bv, bv, bv, bv};
        xg2[g] = (f32x4){0.f, 0.f, 0.f, 0.f};
    }
    // xg += enc @ dWih^T (constant over t; scaled split both operands)
#pragma unroll
    for (int kh = 0; kh < 3; ++kh) {
        half8 eh, els;
#pragma unroll
        for (int j = 0; j < 8; ++j) {
            const float v = enc_lds[l15*100 + kh*32 + lhi*8 + j];
            const _Float16 hi = (_Float16)v;
            eh[j]  = hi;
            els[j] = (_Float16)((v - (float)hi) * SC_LO);
        }
#pragma unroll
        for (int g = 0; g < 4; ++g) {
            const int col = 16*(8*g + w) + l15;
            const float sc = (g == 2) ? 2.0f*L2E : L2E;
            half8 bH, bLs;
#pragma unroll
            for (int j = 0; j < 8; ++j) {
                const float v = dWih[col*96 + kh*32 + lhi*8 + j] * sc;
                const _Float16 hi = (_Float16)v;
                bH[j]  = hi;
                bLs[j] = (_Float16)((v - (float)hi) * SC_LO);
            }
            xg0[g] = MFMA16(eh,  bH,  xg0[g]);
            xg2[g] = MFMA16(eh,  bLs, xg2[g]);
            xg2[g] = MFMA16(els, bH,  xg2[g]);
        }
    }
    f32x4 xg[4];
#pragma unroll
    for (int g = 0; g < 4; ++g)
#pragma unroll
        for (int j = 0; j < 4; ++j) xg[g][j] = xg0[g][j] + xg2[g][j]*IV_LO;

    float c[4] = {0.f, 0.f, 0.f, 0.f};   // (row = lhi*4+j, e = 16w+l15)
    for (int t = 0; t < 16; ++t) {
        f32x4 a0[4], a2[4];
#pragma unroll
        for (int g = 0; g < 4; ++g) { a0[g] = xg[g]; a2[g] = (f32x4){0.f,0.f,0.f,0.f}; }
        if (t > 0) {
#pragma unroll
            for (int kh = 0; kh < 4; ++kh) {
                const int off = l15*136 + kh*32 + lhi*8;
                half8 ah = *(const half8*)&hh_t[off];
                half8 as = *(const half8*)&hl_t[off];
#pragma unroll
                for (int g = 0; g < 4; ++g) {
                    a0[g] = MFMA16(ah, whhH[g][kh],  a0[g]);
                    a2[g] = MFMA16(ah, whhLs[g][kh], a2[g]);
                    a2[g] = MFMA16(as, whhH[g][kh],  a2[g]);
                }
            }
        }
        float hnew[4];
#pragma unroll
        for (int j = 0; j < 4; ++j) {
            const float pi = a0[0][j] + a2[0][j]*IV_LO;
            const float pf = a0[1][j] + a2[1][j]*IV_LO;
            const float pg = a0[2][j] + a2[2][j]*IV_LO;
            const float po = a0[3][j] + a2[3][j]*IV_LO;
            const float si = sigm_s(pi);
            const float sf = sigm_s(pf);
            const float tg = tanh_s(pg);
            const float so = sigm_s(po);
            const float cc = sf * c[j] + si * tg;
            c[j] = cc;
            hnew[j] = so * tanh_s(2.0f*L2E*cc);
        }
        __syncthreads();
#pragma unroll
        for (int j = 0; j < 4; ++j) {
            const int idx = (lhi*4 + j)*136 + 16*w + l15;
            const float v = hnew[j];
            const _Float16 hi = (_Float16)v;
            hh_t[idx] = hi;
            hl_t[idx] = (_Float16)((v - (float)hi) * SC_LO);
        }
        __syncthreads();
        // output head: out = h @ W_out^T + b_out, then activations
        if (tid < 320) {
            const int row = tid / 20, rem = tid % 20, j5 = rem / 4, q = rem % 4;
            float pacc = 0.0f;
#pragma unroll
            for (int e = 0; e < 32; ++e) {
                const int idx = row*136 + q*32 + e;
                pacc += ((float)hh_t[idx] + (float)hl_t[idx]*IV_LO) * wout[j5*132 + q*32 + e];
            }
            part[row][j5][q] = pacc;
        }
        __syncthreads();
        if (tid < 80) {
            const int row = tid / 5, j5 = tid % 5;
            float v = part[row][j5][0] + part[row][j5][1] + part[row][j5][2] + part[row][j5][3] + bout[j5];
            if (j5 == 2 || j5 == 3) v = fexp2(v * L2E);       // exp
            else if (j5 == 4)       v = tanh_s(2.0f*L2E*v);   // tanh
            outp[((size_t)(rb + row)*16 + t)*5 + j5] = v;     // fp32 store
        }
    }
}

// ---------------------------------------------------------------------------
extern "C" void kernel_launch(void* const* d_in, const int* in_sizes, int n_in,
                              void* d_out, int out_size, void* d_ws, size_t ws_size,
                              hipStream_t stream) {
    const float* hist  = (const float*)d_in[0];   // [16][4096][2]
    const float* nbrs  = (const float*)d_in[1];   // [16][131072][2]
    const float* W_inp = (const float*)d_in[2];
    const float* b_inp = (const float*)d_in[3];
    const float* Wih   = (const float*)d_in[4];
    const float* Whh   = (const float*)d_in[5];
    const float* bih   = (const float*)d_in[6];
    const float* bhh   = (const float*)d_in[7];
    const float* W_dym = (const float*)d_in[8];
    const float* b_dym = (const float*)d_in[9];
    const float* W_sp  = (const float*)d_in[10];
    const float* b_sp  = (const float*)d_in[11];
    const float* dWih  = (const float*)d_in[12];
    const float* dWhh  = (const float*)d_in[13];
    const float* dbih  = (const float*)d_in[14];
    const float* dbhh  = (const float*)d_in[15];
    const float* W_out = (const float*)d_in[16];
    const float* b_out = (const float*)d_in[17];
    const void* mask   = (const void*)d_in[18];   // dtype auto-detected on device

    char* ws = (char*)d_ws;
    float* nh32        = (float*)(ws);                    // 131072*64*4 = 33554432
    float* hh32        = (float*)(ws + 33554432);         // 4096*64*4   = 1048576
    float* WspT32      = (float*)(ws + 34603008);         // 169*64*64*4 = 2768896
    unsigned char* pos = (unsigned char*)(ws + 37371904); // 4096*32     = 131072
    float* enc32       = (float*)(ws + 37502976);         // 4096*96*4   = 1572864

    wsp_prep32_kernel<<<2704, 256, 0, stream>>>(W_sp, WspT32);
    pos_prep_kernel<<<1024, 256, 0, stream>>>(mask, pos);
    lstm_enc_kernel<<<2112, 256, 0, stream>>>(hist, nbrs, W_inp, b_inp, Wih, Whh, bih, bhh,
                                              hh32, nh32);
    hist_enc32_kernel<<<512, 256, 0, stream>>>(hh32, W_dym, b_dym, enc32);
    social32_kernel<<<4096, 256, 0, stream>>>(nh32, WspT32, b_sp, pos, enc32);
    decoder_kernel<<<256, 512, 0, stream>>>(enc32, dWih, dWhh, dbih, dbhh, W_out, b_out,
                                            (float*)d_out);
}

// Round 11
// 547.065 us; speedup vs baseline: 1.8696x; 1.8696x over previous
//
#include <hip/hip_runtime.h>
#include <hip/hip_bf16.h>

typedef _Float16 half8 __attribute__((ext_vector_type(8)));
typedef float f32x4 __attribute__((ext_vector_type(4)));

constexpr float L2E   = 1.44269504088896340736f;
constexpr float SC_LO = 4096.0f;        // 2^12, exact
constexpr float IV_LO = 1.0f / 4096.0f; // 2^-12, exact

#define MFMA16(a,b,c) __builtin_amdgcn_mfma_f32_16x16x32_f16((a),(b),(c),0,0,0)

__device__ __forceinline__ float fexp2(float x){ float r; asm("v_exp_f32 %0, %1":"=v"(r):"v"(x)); return r; }
__device__ __forceinline__ float frcp(float x){ float r; asm("v_rcp_f32 %0, %1":"=v"(r):"v"(x)); return r; }

// sigmoid(x) where y = L2E*x was pre-scaled into weights
__device__ __forceinline__ float sigm_s(float y){ return frcp(1.0f + fexp2(-y)); }
// tanh(x) where y = 2*L2E*x was pre-scaled into weights
__device__ __forceinline__ float tanh_s(float y){ return 1.0f - 2.0f*frcp(fexp2(y) + 1.0f); }

// ---------------------------------------------------------------------------
// MEGA kernel: blocks [0,2112) = encoder LSTM (R9-proven config, (256,2), full
// input+recurrent split precision); blocks [2112,4816) = W_sp transpose->fp16;
// blocks [4816,5840) = pos table. Prep blocks are input-independent of the
// encoder so they fill idle CUs concurrently instead of serializing.
// ---------------------------------------------------------------------------
__global__ __launch_bounds__(256, 2)
void mega_enc_kernel(const float* __restrict__ xh,     // hist [16][4096][2]
                     const float* __restrict__ xn,     // nbrs [16][131072][2]
                     const float* __restrict__ W_inp,  // [32][2]
                     const float* __restrict__ b_inp,  // [32]
                     const float* __restrict__ Wih,    // [256][32]
                     const float* __restrict__ Whh,    // [256][64]
                     const float* __restrict__ bih,    // [256]
                     const float* __restrict__ bhh,    // [256]
                     const float* __restrict__ W_sp,   // [64][10816]
                     const void*  __restrict__ mask_raw,
                     float* __restrict__ outh,         // [4096][64] fp32
                     float* __restrict__ outn,         // [131072][64] fp32
                     _Float16* __restrict__ WspT,      // [169][64][64] fp16
                     unsigned char* __restrict__ pos)  // [4096][32]
{
    __shared__ _Float16 h_hi[2][64*72];   // 72-pad; ping-pong
    __shared__ _Float16 h_ls[2][64*72];   // lo * 4096
    const int tid = threadIdx.x;
    const int bid = blockIdx.x;

    if (bid >= 2112) {
        if (bid < 2112 + 2704) {
            // ---- W_spT[p][e][s] = W_sp[s][e*169+p] (fp16) ----
            const int idx = (bid - 2112) * 256 + tid;
            if (idx < 64 * 10816) {
                const int s = idx / 10816, cidx = idx % 10816;
                const int e = cidx / 169, p = cidx % 169;
                WspT[((size_t)p*64 + e)*64 + s] = (_Float16)W_sp[idx];
            }
        } else {
            // ---- pos[b][k]: rank of occupied cells (mask dtype auto-detect) ----
            const int agent = (bid - 4816) * 4 + (tid >> 6);
            const int l = tid & 63;
            if (agent < 4096) {
                if (l < 32) pos[agent*32 + l] = 0;
                const unsigned char* raw = (const unsigned char*)mask_raw;
                const int* mi = (const int*)mask_raw;
                int mism = 0;
#pragma unroll
                for (int ch = 0; ch < 3; ++ch) {
                    const int cc = ch*64 + l;
                    if (cc < 169) {
                        const unsigned char b0 = raw[cc*64], b1 = raw[cc*64 + 1];
                        mism |= (b0 != 0 && b1 == 0) ? 1 : 0;
                    }
                }
                const bool is_i32 = (__ballot(mism != 0) != 0ull);
                int base = 0;
#pragma unroll
                for (int ch = 0; ch < 3; ++ch) {
                    const int cc = ch*64 + l;
                    bool occ = false;
                    if (cc < 169) {
                        const size_t ei = (size_t)agent * 10816 + (size_t)cc * 64;
                        occ = is_i32 ? (mi[ei] != 0) : (raw[ei] != 0);
                    }
                    const unsigned long long bal = __ballot(occ);
                    if (occ) {
                        const int rank = base + __popcll(bal & ((1ull << l) - 1ull));
                        const int gh = cc / 13, gw = cc % 13;
                        if (rank < 32)
                            pos[agent*32 + rank] = (unsigned char)(gw*13 + gh);
                    }
                    base += __popcll(bal);
                }
            }
        }
        return;
    }

    // ======================= encoder (R9-proven) ===========================
    const int w   = tid >> 6;
    const int l   = tid & 63;
    const int l15 = l & 15, lhi = l >> 4;

    const bool is_hist = (bid < 64);
    const float* x = is_hist ? xh : xn;
    float* out     = is_hist ? outh : outn;
    const int N    = is_hist ? 4096 : 131072;
    const int rbase = (is_hist ? bid : (bid - 64)) * 64;

    // resident split B-fragments (scaled by gate factor; lo scaled by 2^12)
    half8 whhH[4][2], whhLs[4][2];  // [gate][khalf]
    half8 wihH[4], wihLs[4];
    float bias[4];
#pragma unroll
    for (int g = 0; g < 4; ++g) {
        const int col = 16*(w + 4*g) + l15;           // global gate column
        const float sc = (g == 2) ? 2.0f*L2E : L2E;
#pragma unroll
        for (int kh = 0; kh < 2; ++kh)
#pragma unroll
            for (int j = 0; j < 8; ++j) {
                const float v = Whh[col*64 + kh*32 + lhi*8 + j] * sc;
                const _Float16 hi = (_Float16)v;
                whhH[g][kh][j]  = hi;
                whhLs[g][kh][j] = (_Float16)((v - (float)hi) * SC_LO);
            }
#pragma unroll
        for (int j = 0; j < 8; ++j) {
            const float v = Wih[col*32 + lhi*8 + j] * sc;
            const _Float16 hi = (_Float16)v;
            wihH[g][j]  = hi;
            wihLs[g][j] = (_Float16)((v - (float)hi) * SC_LO);
        }
        bias[g] = (bih[col] + bhh[col]) * sc;
    }
    // W_inp columns for this lane's emb A-frag slots (k = lhi*8 + j)
    float w0[8], w1[8], bb[8];
#pragma unroll
    for (int j = 0; j < 8; ++j) {
        const int k = lhi*8 + j;
        w0[j] = W_inp[k*2 + 0]; w1[j] = W_inp[k*2 + 1]; bb[j] = b_inp[k];
    }

    float c[4][4];   // cell state: (row = 16m + lhi*4 + j, e = 16w + l15)
#pragma unroll
    for (int m = 0; m < 4; ++m)
#pragma unroll
        for (int j = 0; j < 4; ++j) c[m][j] = 0.0f;

    const float2* xp = (const float2*)x;
    float2 xc[4];
#pragma unroll
    for (int m = 0; m < 4; ++m)
        xc[m] = xp[(size_t)0*N + rbase + 16*m + l15];

#pragma unroll 1
    for (int t = 0; t < 16; ++t) {
        const int rdb = (t + 1) & 1;   // h(t-1) buffer
        const int wrb = t & 1;         // h(t) buffer
        float hnew[4][4];
#pragma unroll
        for (int m = 0; m < 4; ++m) {
            // emb split (lo scaled)
            half8 eh, els;
#pragma unroll
            for (int j = 0; j < 8; ++j) {
                float v = xc[m].x * w0[j] + xc[m].y * w1[j] + bb[j];
                v = fmaxf(v, 0.1f * v);            // leaky relu
                const _Float16 hi = (_Float16)v;
                eh[j]  = hi;
                els[j] = (_Float16)((v - (float)hi) * SC_LO);
            }
            f32x4 a0[4], a2[4];
#pragma unroll
            for (int g = 0; g < 4; ++g) {
                a0[g] = (f32x4){bias[g], bias[g], bias[g], bias[g]};
                a2[g] = (f32x4){0.f, 0.f, 0.f, 0.f};
            }
#pragma unroll
            for (int g = 0; g < 4; ++g) {
                a0[g] = MFMA16(eh,  wihH[g],  a0[g]);
                a2[g] = MFMA16(eh,  wihLs[g], a2[g]);
                a2[g] = MFMA16(els, wihH[g],  a2[g]);
            }
            if (t > 0) {
#pragma unroll
                for (int kh = 0; kh < 2; ++kh) {
                    const int off = (16*m + l15)*72 + kh*32 + lhi*8;
                    half8 ah = *(const half8*)&h_hi[rdb][off];
                    half8 as = *(const half8*)&h_ls[rdb][off];
#pragma unroll
                    for (int g = 0; g < 4; ++g) {
                        a0[g] = MFMA16(ah, whhH[g][kh],  a0[g]);
                        a2[g] = MFMA16(ah, whhLs[g][kh], a2[g]);
                        a2[g] = MFMA16(as, whhH[g][kh],  a2[g]);
                    }
                }
            }
            // gates for this m-tile
#pragma unroll
            for (int j = 0; j < 4; ++j) {
                const float pi = a0[0][j] + a2[0][j]*IV_LO;
                const float pf = a0[1][j] + a2[1][j]*IV_LO;
                const float pg = a0[2][j] + a2[2][j]*IV_LO;
                const float po = a0[3][j] + a2[3][j]*IV_LO;
                const float si = sigm_s(pi);
                const float sf = sigm_s(pf);
                const float tg = tanh_s(pg);
                const float so = sigm_s(po);
                const float cc = sf * c[m][j] + si * tg;
                c[m][j] = cc;
                hnew[m][j] = so * tanh_s(2.0f*L2E*cc);
            }
        }
        // write h(t) to the OTHER buffer — no pre-barrier needed
#pragma unroll
        for (int m = 0; m < 4; ++m)
#pragma unroll
            for (int j = 0; j < 4; ++j) {
                const int idx = (16*m + lhi*4 + j)*72 + 16*w + l15;
                const float v = hnew[m][j];
                const _Float16 hi = (_Float16)v;
                h_hi[wrb][idx] = hi;
                h_ls[wrb][idx] = (_Float16)((v - (float)hi) * SC_LO);
            }
        __syncthreads();   // h(t) visible; h(t-1) reads were all pre-write
        if (t < 15) {
#pragma unroll
            for (int m = 0; m < 4; ++m)
                xc[m] = xp[(size_t)(t+1)*N + rbase + 16*m + l15];
        }
    }
    // coalesced fp32 output of final h (in buf[15&1]=1): hi + lo*2^-12
    {
        const int row = tid >> 2, c0 = (tid & 3) * 16;
        const size_t g = (size_t)(rbase + row) * 64 + c0;
#pragma unroll
        for (int i = 0; i < 16; ++i) {
            const int idx = row*72 + c0 + i;
            out[g + i] = (float)h_hi[1][idx] + (float)h_ls[1][idx] * IV_LO;
        }
    }
}

// ---------------------------------------------------------------------------
// social[b][s] = lrelu(b_sp[s] + sum_k sum_e nh[b*32+k][e]*WspT[p_k][e][s])
// -> enc[:, 32:96]; ALSO computes hist_enc -> enc[:, 0:32] (merged dispatch).
// WspT is fp16 (halves the ~2GB L2 gather traffic).
// ---------------------------------------------------------------------------
__global__ __launch_bounds__(256)
void social_kernel(const float* __restrict__ nh,      // [131072][64] fp32
                   const float* __restrict__ hh,      // [4096][64] fp32
                   const _Float16* __restrict__ WspT, // [169][64][64] fp16
                   const float* __restrict__ b_sp,    // [64]
                   const float* __restrict__ W_dym,   // [32][64]
                   const float* __restrict__ b_dym,   // [32]
                   const unsigned char* __restrict__ pos, // [4096][32]
                   float* __restrict__ enc)           // [4096][96]
{
    __shared__ float part[4][64];
    __shared__ unsigned char pl[32];
    const int tid = threadIdx.x, b = blockIdx.x;
    if (tid < 32) {
        const int p = pos[b*32 + tid];
        pl[tid] = (unsigned char)(p > 168 ? 0 : p);
    }
    __syncthreads();
    const int s = tid & 63, kq = tid >> 6;
    float a = 0.f;
    for (int kk = 0; kk < 8; ++kk) {
        const int k = kq*8 + kk;
        const float* nr = nh + ((size_t)b*32 + k) * 64;
        const _Float16* wp = WspT + (size_t)pl[k] * 4096 + s;
#pragma unroll
        for (int e = 0; e < 64; ++e) a += nr[e] * (float)wp[(size_t)e * 64];
    }
    part[kq][s] = a;
    __syncthreads();
    if (tid < 64) {
        const float v = part[0][tid] + part[1][tid] + part[2][tid] + part[3][tid] + b_sp[tid];
        enc[(size_t)b * 96 + 32 + tid] = fmaxf(v, 0.1f * v);
    } else if (tid >= 64 && tid < 96) {
        // hist_enc for this agent: enc[b][0:32]
        const int so = tid - 64;
        float ah = b_dym[so];
        const float* hr = hh + (size_t)b * 64;
        const float* wr = W_dym + (size_t)so * 64;
#pragma unroll
        for (int e = 0; e < 64; ++e) ah += hr[e] * wr[e];
        enc[(size_t)b * 96 + so] = fmaxf(ah, 0.1f * ah);
    }
}

// ---------------------------------------------------------------------------
// Decoder LSTM (128 hidden, 16 steps, xg constant over t) + head.
// Scaled split-precision recurrent path; fp32 enc input; fp32 output.
// Block: 512 thr (8 waves), 16 rows.
// ---------------------------------------------------------------------------
__global__ __launch_bounds__(512, 1)
void decoder_kernel(const float* __restrict__ enc,    // [4096][96] fp32
                    const float* __restrict__ dWih,   // [512][96]
                    const float* __restrict__ dWhh,   // [512][128]
                    const float* __restrict__ dbih,   // [512]
                    const float* __restrict__ dbhh,   // [512]
                    const float* __restrict__ W_out,  // [5][128]
                    const float* __restrict__ b_out,  // [5]
                    float* __restrict__ outp)         // [4096][16][5] fp32
{
    __shared__ float enc_lds[16*100];    // stride 100 floats (400B, 16B-aligned)
    __shared__ _Float16 hh_t[16*136];
    __shared__ _Float16 hl_t[16*136];    // lo * 4096
    __shared__ float wout[5*132];
    __shared__ float bout[5];
    __shared__ float part[16][5][4];
    const int tid = threadIdx.x;
    const int w = tid >> 6, l = tid & 63, l15 = l & 15, lhi = l >> 4;
    const int rb = blockIdx.x * 16;

    if (tid < 384) {
        const int row = tid / 24, ch = tid % 24;
        *(float4*)&enc_lds[row*100 + ch*4] = *(const float4*)&enc[(size_t)(rb + row)*96 + ch*4];
    }
    for (int i = tid; i < 640; i += 512) { const int j = i / 128, e = i % 128; wout[j*132 + e] = W_out[i]; }
    if (tid < 5) bout[tid] = b_out[tid];
    __syncthreads();

    half8 whhH[4][4], whhLs[4][4];  // [gate][khalf]
    f32x4 xg0[4], xg2[4];
#pragma unroll
    for (int g = 0; g < 4; ++g) {
        const int col = 16*(8*g + w) + l15;
        const float sc = (g == 2) ? 2.0f*L2E : L2E;
#pragma unroll
        for (int kh = 0; kh < 4; ++kh)
#pragma unroll
            for (int j = 0; j < 8; ++j) {
                const float v = dWhh[col*128 + kh*32 + lhi*8 + j] * sc;
                const _Float16 hi = (_Float16)v;
                whhH[g][kh][j]  = hi;
                whhLs[g][kh][j] = (_Float16)((v - (float)hi) * SC_LO);
            }
        const float bv = (dbih[col] + dbhh[col]) * sc;
        xg0[g] = (f32x4){bv, bv, bv, bv};
        xg2[g] = (f32x4){0.f, 0.f, 0.f, 0.f};
    }
    // xg += enc @ dWih^T (constant over t; scaled split both operands)
#pragma unroll
    for (int kh = 0; kh < 3; ++kh) {
        half8 eh, els;
#pragma unroll
        for (int j = 0; j < 8; ++j) {
            const float v = enc_lds[l15*100 + kh*32 + lhi*8 + j];
            const _Float16 hi = (_Float16)v;
            eh[j]  = hi;
            els[j] = (_Float16)((v - (float)hi) * SC_LO);
        }
#pragma unroll
        for (int g = 0; g < 4; ++g) {
            const int col = 16*(8*g + w) + l15;
            const float sc = (g == 2) ? 2.0f*L2E : L2E;
            half8 bH, bLs;
#pragma unroll
            for (int j = 0; j < 8; ++j) {
                const float v = dWih[col*96 + kh*32 + lhi*8 + j] * sc;
                const _Float16 hi = (_Float16)v;
                bH[j]  = hi;
                bLs[j] = (_Float16)((v - (float)hi) * SC_LO);
            }
            xg0[g] = MFMA16(eh,  bH,  xg0[g]);
            xg2[g] = MFMA16(eh,  bLs, xg2[g]);
            xg2[g] = MFMA16(els, bH,  xg2[g]);
        }
    }
    f32x4 xg[4];
#pragma unroll
    for (int g = 0; g < 4; ++g)
#pragma unroll
        for (int j = 0; j < 4; ++j) xg[g][j] = xg0[g][j] + xg2[g][j]*IV_LO;

    float c[4] = {0.f, 0.f, 0.f, 0.f};   // (row = lhi*4+j, e = 16w+l15)
#pragma unroll 1
    for (int t = 0; t < 16; ++t) {
        f32x4 a0[4], a2[4];
#pragma unroll
        for (int g = 0; g < 4; ++g) { a0[g] = xg[g]; a2[g] = (f32x4){0.f,0.f,0.f,0.f}; }
        if (t > 0) {
#pragma unroll
            for (int kh = 0; kh < 4; ++kh) {
                const int off = l15*136 + kh*32 + lhi*8;
                half8 ah = *(const half8*)&hh_t[off];
                half8 as = *(const half8*)&hl_t[off];
#pragma unroll
                for (int g = 0; g < 4; ++g) {
                    a0[g] = MFMA16(ah, whhH[g][kh],  a0[g]);
                    a2[g] = MFMA16(ah, whhLs[g][kh], a2[g]);
                    a2[g] = MFMA16(as, whhH[g][kh],  a2[g]);
                }
            }
        }
        float hnew[4];
#pragma unroll
        for (int j = 0; j < 4; ++j) {
            const float pi = a0[0][j] + a2[0][j]*IV_LO;
            const float pf = a0[1][j] + a2[1][j]*IV_LO;
            const float pg = a0[2][j] + a2[2][j]*IV_LO;
            const float po = a0[3][j] + a2[3][j]*IV_LO;
            const float si = sigm_s(pi);
            const float sf = sigm_s(pf);
            const float tg = tanh_s(pg);
            const float so = sigm_s(po);
            const float cc = sf * c[j] + si * tg;
            c[j] = cc;
            hnew[j] = so * tanh_s(2.0f*L2E*cc);
        }
        __syncthreads();
#pragma unroll
        for (int j = 0; j < 4; ++j) {
            const int idx = (lhi*4 + j)*136 + 16*w + l15;
            const float v = hnew[j];
            const _Float16 hi = (_Float16)v;
            hh_t[idx] = hi;
            hl_t[idx] = (_Float16)((v - (float)hi) * SC_LO);
        }
        __syncthreads();
        // output head: out = h @ W_out^T + b_out, then activations
        if (tid < 320) {
            const int row = tid / 20, rem = tid % 20, j5 = rem / 4, q = rem % 4;
            float pacc = 0.0f;
#pragma unroll
            for (int e = 0; e < 32; ++e) {
                const int idx = row*136 + q*32 + e;
                pacc += ((float)hh_t[idx] + (float)hl_t[idx]*IV_LO) * wout[j5*132 + q*32 + e];
            }
            part[row][j5][q] = pacc;
        }
        __syncthreads();
        if (tid < 80) {
            const int row = tid / 5, j5 = tid % 5;
            float v = part[row][j5][0] + part[row][j5][1] + part[row][j5][2] + part[row][j5][3] + bout[j5];
            if (j5 == 2 || j5 == 3) v = fexp2(v * L2E);       // exp
            else if (j5 == 4)       v = tanh_s(2.0f*L2E*v);   // tanh
            outp[((size_t)(rb + row)*16 + t)*5 + j5] = v;     // fp32 store
        }
    }
}

// ---------------------------------------------------------------------------
extern "C" void kernel_launch(void* const* d_in, const int* in_sizes, int n_in,
                              void* d_out, int out_size, void* d_ws, size_t ws_size,
                              hipStream_t stream) {
    const float* hist  = (const float*)d_in[0];   // [16][4096][2]
    const float* nbrs  = (const float*)d_in[1];   // [16][131072][2]
    const float* W_inp = (const float*)d_in[2];
    const float* b_inp = (const float*)d_in[3];
    const float* Wih   = (const float*)d_in[4];
    const float* Whh   = (const float*)d_in[5];
    const float* bih   = (const float*)d_in[6];
    const float* bhh   = (const float*)d_in[7];
    const float* W_dym = (const float*)d_in[8];
    const float* b_dym = (const float*)d_in[9];
    const float* W_sp  = (const float*)d_in[10];
    const float* b_sp  = (const float*)d_in[11];
    const float* dWih  = (const float*)d_in[12];
    const float* dWhh  = (const float*)d_in[13];
    const float* dbih  = (const float*)d_in[14];
    const float* dbhh  = (const float*)d_in[15];
    const float* W_out = (const float*)d_in[16];
    const float* b_out = (const float*)d_in[17];
    const void* mask   = (const void*)d_in[18];   // dtype auto-detected on device

    char* ws = (char*)d_ws;
    float* nh32        = (float*)(ws);                    // 131072*64*4 = 33554432
    float* hh32        = (float*)(ws + 33554432);         // 4096*64*4   = 1048576
    _Float16* WspT16   = (_Float16*)(ws + 34603008);      // 169*64*64*2 = 1384448
    unsigned char* pos = (unsigned char*)(ws + 35987456); // 4096*32     = 131072
    float* enc32       = (float*)(ws + 36118528);         // 4096*96*4   = 1572864

    mega_enc_kernel<<<5840, 256, 0, stream>>>(hist, nbrs, W_inp, b_inp, Wih, Whh, bih, bhh,
                                              W_sp, mask, hh32, nh32, WspT16, pos);
    social_kernel<<<4096, 256, 0, stream>>>(nh32, hh32, WspT16, b_sp, W_dym, b_dym, pos, enc32);
    decoder_kernel<<<256, 512, 0, stream>>>(enc32, dWih, dWhh, dbih, dbhh, W_out, b_out,
                                            (float*)d_out);
}

// Round 12
// 482.127 us; speedup vs baseline: 2.1214x; 1.1347x over previous
//
#include <hip/hip_runtime.h>
#include <hip/hip_bf16.h>

typedef _Float16 half8 __attribute__((ext_vector_type(8)));
typedef _Float16 half2v __attribute__((ext_vector_type(2)));
typedef float f32x4 __attribute__((ext_vector_type(4)));

constexpr float L2E   = 1.44269504088896340736f;
constexpr float SC_LO = 4096.0f;        // 2^12, exact
constexpr float IV_LO = 1.0f / 4096.0f; // 2^-12, exact

#define MFMA16(a,b,c) __builtin_amdgcn_mfma_f32_16x16x32_f16((a),(b),(c),0,0,0)

__device__ __forceinline__ float fexp2(float x){ float r; asm("v_exp_f32 %0, %1":"=v"(r):"v"(x)); return r; }
__device__ __forceinline__ float frcp(float x){ float r; asm("v_rcp_f32 %0, %1":"=v"(r):"v"(x)); return r; }

// sigmoid(x) where y = L2E*x was pre-scaled into weights
__device__ __forceinline__ float sigm_s(float y){ return frcp(1.0f + fexp2(-y)); }
// tanh(x) where y = 2*L2E*x was pre-scaled into weights
__device__ __forceinline__ float tanh_s(float y){ return 1.0f - 2.0f*frcp(fexp2(y) + 1.0f); }

// ---------------------------------------------------------------------------
// MEGA kernel: blocks [0,2112) = encoder LSTM; [2112,4816) = W_sp->fp16
// transpose; [4816,5840) = pos table (concurrent prep, R11-proven).
// Encoder register diet vs R11: no hnew array (direct ping-pong writes),
// input path hi-only (R10-measured 7.8e-3), fp16-packed emb weights.
// Target: true demand <=170 regs so HW fits 3 waves/SIMD under the SAME
// (256,2) bound (no forced cap => no spill risk; R8/R10 lesson).
// ---------------------------------------------------------------------------
__global__ __launch_bounds__(256, 2)
void mega_enc_kernel(const float* __restrict__ xh,     // hist [16][4096][2]
                     const float* __restrict__ xn,     // nbrs [16][131072][2]
                     const float* __restrict__ W_inp,  // [32][2]
                     const float* __restrict__ b_inp,  // [32]
                     const float* __restrict__ Wih,    // [256][32]
                     const float* __restrict__ Whh,    // [256][64]
                     const float* __restrict__ bih,    // [256]
                     const float* __restrict__ bhh,    // [256]
                     const float* __restrict__ W_sp,   // [64][10816]
                     const void*  __restrict__ mask_raw,
                     float* __restrict__ outh,         // [4096][64] fp32
                     float* __restrict__ outn,         // [131072][64] fp32
                     _Float16* __restrict__ WspT,      // [169][64][64] fp16
                     unsigned char* __restrict__ pos)  // [4096][32]
{
    __shared__ _Float16 h_hi[2][64*72];   // 72-pad; ping-pong
    __shared__ _Float16 h_ls[2][64*72];   // lo * 4096
    const int tid = threadIdx.x;
    const int bid = blockIdx.x;

    if (bid >= 2112) {
        if (bid < 2112 + 2704) {
            // ---- W_spT[p][e][s] = W_sp[s][e*169+p] (fp16) ----
            const int idx = (bid - 2112) * 256 + tid;
            if (idx < 64 * 10816) {
                const int s = idx / 10816, cidx = idx % 10816;
                const int e = cidx / 169, p = cidx % 169;
                WspT[((size_t)p*64 + e)*64 + s] = (_Float16)W_sp[idx];
            }
        } else {
            // ---- pos[b][k]: rank of occupied cells (mask dtype auto-detect) ----
            const int agent = (bid - 4816) * 4 + (tid >> 6);
            const int l = tid & 63;
            if (agent < 4096) {
                if (l < 32) pos[agent*32 + l] = 0;
                const unsigned char* raw = (const unsigned char*)mask_raw;
                const int* mi = (const int*)mask_raw;
                int mism = 0;
#pragma unroll
                for (int ch = 0; ch < 3; ++ch) {
                    const int cc = ch*64 + l;
                    if (cc < 169) {
                        const unsigned char b0 = raw[cc*64], b1 = raw[cc*64 + 1];
                        mism |= (b0 != 0 && b1 == 0) ? 1 : 0;
                    }
                }
                const bool is_i32 = (__ballot(mism != 0) != 0ull);
                int base = 0;
#pragma unroll
                for (int ch = 0; ch < 3; ++ch) {
                    const int cc = ch*64 + l;
                    bool occ = false;
                    if (cc < 169) {
                        const size_t ei = (size_t)agent * 10816 + (size_t)cc * 64;
                        occ = is_i32 ? (mi[ei] != 0) : (raw[ei] != 0);
                    }
                    const unsigned long long bal = __ballot(occ);
                    if (occ) {
                        const int rank = base + __popcll(bal & ((1ull << l) - 1ull));
                        const int gh = cc / 13, gw = cc % 13;
                        if (rank < 32)
                            pos[agent*32 + rank] = (unsigned char)(gw*13 + gh);
                    }
                    base += __popcll(bal);
                }
            }
        }
        return;
    }

    // ======================= encoder ===========================
    const int w   = tid >> 6;
    const int l   = tid & 63;
    const int l15 = l & 15, lhi = l >> 4;

    const bool is_hist = (bid < 64);
    const float* x = is_hist ? xh : xn;
    float* out     = is_hist ? outh : outn;
    const int N    = is_hist ? 4096 : 131072;
    const int rbase = (is_hist ? bid : (bid - 64)) * 64;

    // resident B-fragments: recurrent split (hi + 2^12*lo), input hi-only
    half8 whhH[4][2], whhLs[4][2];  // [gate][khalf]
    half8 wihH[4];
    float bias[4];
#pragma unroll
    for (int g = 0; g < 4; ++g) {
        const int col = 16*(w + 4*g) + l15;           // global gate column
        const float sc = (g == 2) ? 2.0f*L2E : L2E;
#pragma unroll
        for (int kh = 0; kh < 2; ++kh)
#pragma unroll
            for (int j = 0; j < 8; ++j) {
                const float v = Whh[col*64 + kh*32 + lhi*8 + j] * sc;
                const _Float16 hi = (_Float16)v;
                whhH[g][kh][j]  = hi;
                whhLs[g][kh][j] = (_Float16)((v - (float)hi) * SC_LO);
            }
#pragma unroll
        for (int j = 0; j < 8; ++j)
            wihH[g][j] = (_Float16)(Wih[col*32 + lhi*8 + j] * sc);
        bias[g] = (bih[col] + bhh[col]) * sc;
    }
    // emb weights for this lane's k-slots (k = lhi*8 + j): fp16-packed (w0,w1)
    half2v w01[8];
    float bb[8];
#pragma unroll
    for (int j = 0; j < 8; ++j) {
        const int k = lhi*8 + j;
        w01[j][0] = (_Float16)W_inp[k*2 + 0];
        w01[j][1] = (_Float16)W_inp[k*2 + 1];
        bb[j] = b_inp[k];
    }

    float c[4][4];   // cell state: (row = 16m + lhi*4 + j, e = 16w + l15)
#pragma unroll
    for (int m = 0; m < 4; ++m)
#pragma unroll
        for (int j = 0; j < 4; ++j) c[m][j] = 0.0f;

    const float2* xp = (const float2*)x;
    float2 xc[4];
#pragma unroll
    for (int m = 0; m < 4; ++m)
        xc[m] = xp[(size_t)0*N + rbase + 16*m + l15];

#pragma unroll 1
    for (int t = 0; t < 16; ++t) {
        const int rdb = (t + 1) & 1;   // h(t-1) buffer
        const int wrb = t & 1;         // h(t) buffer
#pragma unroll
        for (int m = 0; m < 4; ++m) {
            // emb (hi-only, fp16 weights)
            half8 eh;
#pragma unroll
            for (int j = 0; j < 8; ++j) {
                float v = xc[m].x * (float)w01[j][0] + xc[m].y * (float)w01[j][1] + bb[j];
                v = fmaxf(v, 0.1f * v);            // leaky relu
                eh[j] = (_Float16)v;
            }
            f32x4 a0[4], a2[4];
#pragma unroll
            for (int g = 0; g < 4; ++g) {
                a0[g] = (f32x4){bias[g], bias[g], bias[g], bias[g]};
                a2[g] = (f32x4){0.f, 0.f, 0.f, 0.f};
            }
#pragma unroll
            for (int g = 0; g < 4; ++g)
                a0[g] = MFMA16(eh, wihH[g], a0[g]);
            if (t > 0) {
#pragma unroll
                for (int kh = 0; kh < 2; ++kh) {
                    const int off = (16*m + l15)*72 + kh*32 + lhi*8;
                    half8 ah = *(const half8*)&h_hi[rdb][off];
                    half8 as = *(const half8*)&h_ls[rdb][off];
#pragma unroll
                    for (int g = 0; g < 4; ++g) {
                        a0[g] = MFMA16(ah, whhH[g][kh],  a0[g]);
                        a2[g] = MFMA16(ah, whhLs[g][kh], a2[g]);
                        a2[g] = MFMA16(as, whhH[g][kh],  a2[g]);
                    }
                }
            }
            // gates for this m-tile; write h(t) directly (other buffer => safe)
#pragma unroll
            for (int j = 0; j < 4; ++j) {
                const float pi = a0[0][j] + a2[0][j]*IV_LO;
                const float pf = a0[1][j] + a2[1][j]*IV_LO;
                const float pg = a0[2][j] + a2[2][j]*IV_LO;
                const float po = a0[3][j] + a2[3][j]*IV_LO;
                const float si = sigm_s(pi);
                const float sf = sigm_s(pf);
                const float tg = tanh_s(pg);
                const float so = sigm_s(po);
                const float cc = sf * c[m][j] + si * tg;
                c[m][j] = cc;
                const float hv = so * tanh_s(2.0f*L2E*cc);
                const int idx = (16*m + lhi*4 + j)*72 + 16*w + l15;
                const _Float16 hi = (_Float16)hv;
                h_hi[wrb][idx] = hi;
                h_ls[wrb][idx] = (_Float16)((hv - (float)hi) * SC_LO);
            }
        }
        __syncthreads();   // h(t) visible; h(t-1) reads were from other buffer
        if (t < 15) {
#pragma unroll
            for (int m = 0; m < 4; ++m)
                xc[m] = xp[(size_t)(t+1)*N + rbase + 16*m + l15];
        }
    }
    // coalesced fp32 output of final h (in buf[15&1]=1): hi + lo*2^-12
    {
        const int row = tid >> 2, c0 = (tid & 3) * 16;
        const size_t g = (size_t)(rbase + row) * 64 + c0;
#pragma unroll
        for (int i = 0; i < 16; ++i) {
            const int idx = row*72 + c0 + i;
            out[g + i] = (float)h_hi[1][idx] + (float)h_ls[1][idx] * IV_LO;
        }
    }
}

// ---------------------------------------------------------------------------
// social[b][s] = lrelu(b_sp[s] + sum_k sum_e nh[b*32+k][e]*WspT[p_k][e][s])
// -> enc[:, 32:96]; ALSO computes hist_enc -> enc[:, 0:32] (merged dispatch).
// ---------------------------------------------------------------------------
__global__ __launch_bounds__(256)
void social_kernel(const float* __restrict__ nh,      // [131072][64] fp32
                   const float* __restrict__ hh,      // [4096][64] fp32
                   const _Float16* __restrict__ WspT, // [169][64][64] fp16
                   const float* __restrict__ b_sp,    // [64]
                   const float* __restrict__ W_dym,   // [32][64]
                   const float* __restrict__ b_dym,   // [32]
                   const unsigned char* __restrict__ pos, // [4096][32]
                   float* __restrict__ enc)           // [4096][96]
{
    __shared__ float part[4][64];
    __shared__ unsigned char pl[32];
    const int tid = threadIdx.x, b = blockIdx.x;
    if (tid < 32) {
        const int p = pos[b*32 + tid];
        pl[tid] = (unsigned char)(p > 168 ? 0 : p);
    }
    __syncthreads();
    const int s = tid & 63, kq = tid >> 6;
    float a = 0.f;
    for (int kk = 0; kk < 8; ++kk) {
        const int k = kq*8 + kk;
        const float* nr = nh + ((size_t)b*32 + k) * 64;
        const _Float16* wp = WspT + (size_t)pl[k] * 4096 + s;
#pragma unroll
        for (int e = 0; e < 64; ++e) a += nr[e] * (float)wp[(size_t)e * 64];
    }
    part[kq][s] = a;
    __syncthreads();
    if (tid < 64) {
        const float v = part[0][tid] + part[1][tid] + part[2][tid] + part[3][tid] + b_sp[tid];
        enc[(size_t)b * 96 + 32 + tid] = fmaxf(v, 0.1f * v);
    } else if (tid >= 64 && tid < 96) {
        // hist_enc for this agent: enc[b][0:32]
        const int so = tid - 64;
        float ah = b_dym[so];
        const float* hr = hh + (size_t)b * 64;
        const float* wr = W_dym + (size_t)so * 64;
#pragma unroll
        for (int e = 0; e < 64; ++e) ah += hr[e] * wr[e];
        enc[(size_t)b * 96 + so] = fmaxf(ah, 0.1f * ah);
    }
}

// ---------------------------------------------------------------------------
// Decoder LSTM (128 hidden, 16 steps, xg constant over t) + head.
// Scaled split-precision recurrent path; fp32 enc input; fp32 output.
// Block: 512 thr (8 waves), 16 rows.
// ---------------------------------------------------------------------------
__global__ __launch_bounds__(512, 1)
void decoder_kernel(const float* __restrict__ enc,    // [4096][96] fp32
                    const float* __restrict__ dWih,   // [512][96]
                    const float* __restrict__ dWhh,   // [512][128]
                    const float* __restrict__ dbih,   // [512]
                    const float* __restrict__ dbhh,   // [512]
                    const float* __restrict__ W_out,  // [5][128]
                    const float* __restrict__ b_out,  // [5]
                    float* __restrict__ outp)         // [4096][16][5] fp32
{
    __shared__ float enc_lds[16*100];    // stride 100 floats (400B, 16B-aligned)
    __shared__ _Float16 hh_t[16*136];
    __shared__ _Float16 hl_t[16*136];    // lo * 4096
    __shared__ float wout[5*132];
    __shared__ float bout[5];
    __shared__ float part[16][5][4];
    const int tid = threadIdx.x;
    const int w = tid >> 6, l = tid & 63, l15 = l & 15, lhi = l >> 4;
    const int rb = blockIdx.x * 16;

    if (tid < 384) {
        const int row = tid / 24, ch = tid % 24;
        *(float4*)&enc_lds[row*100 + ch*4] = *(const float4*)&enc[(size_t)(rb + row)*96 + ch*4];
    }
    for (int i = tid; i < 640; i += 512) { const int j = i / 128, e = i % 128; wout[j*132 + e] = W_out[i]; }
    if (tid < 5) bout[tid] = b_out[tid];
    __syncthreads();

    half8 whhH[4][4], whhLs[4][4];  // [gate][khalf]
    f32x4 xg0[4], xg2[4];
#pragma unroll
    for (int g = 0; g < 4; ++g) {
        const int col = 16*(8*g + w) + l15;
        const float sc = (g == 2) ? 2.0f*L2E : L2E;
#pragma unroll
        for (int kh = 0; kh < 4; ++kh)
#pragma unroll
            for (int j = 0; j < 8; ++j) {
                const float v = dWhh[col*128 + kh*32 + lhi*8 + j] * sc;
                const _Float16 hi = (_Float16)v;
                whhH[g][kh][j]  = hi;
                whhLs[g][kh][j] = (_Float16)((v - (float)hi) * SC_LO);
            }
        const float bv = (dbih[col] + dbhh[col]) * sc;
        xg0[g] = (f32x4){bv, bv, bv, bv};
        xg2[g] = (f32x4){0.f, 0.f, 0.f, 0.f};
    }
    // xg += enc @ dWih^T (constant over t; scaled split both operands)
#pragma unroll
    for (int kh = 0; kh < 3; ++kh) {
        half8 eh, els;
#pragma unroll
        for (int j = 0; j < 8; ++j) {
            const float v = enc_lds[l15*100 + kh*32 + lhi*8 + j];
            const _Float16 hi = (_Float16)v;
            eh[j]  = hi;
            els[j] = (_Float16)((v - (float)hi) * SC_LO);
        }
#pragma unroll
        for (int g = 0; g < 4; ++g) {
            const int col = 16*(8*g + w) + l15;
            const float sc = (g == 2) ? 2.0f*L2E : L2E;
            half8 bH, bLs;
#pragma unroll
            for (int j = 0; j < 8; ++j) {
                const float v = dWih[col*96 + kh*32 + lhi*8 + j] * sc;
                const _Float16 hi = (_Float16)v;
                bH[j]  = hi;
                bLs[j] = (_Float16)((v - (float)hi) * SC_LO);
            }
            xg0[g] = MFMA16(eh,  bH,  xg0[g]);
            xg2[g] = MFMA16(eh,  bLs, xg2[g]);
            xg2[g] = MFMA16(els, bH,  xg2[g]);
        }
    }
    f32x4 xg[4];
#pragma unroll
    for (int g = 0; g < 4; ++g)
#pragma unroll
        for (int j = 0; j < 4; ++j) xg[g][j] = xg0[g][j] + xg2[g][j]*IV_LO;

    float c[4] = {0.f, 0.f, 0.f, 0.f};   // (row = lhi*4+j, e = 16w+l15)
#pragma unroll 1
    for (int t = 0; t < 16; ++t) {
        f32x4 a0[4], a2[4];
#pragma unroll
        for (int g = 0; g < 4; ++g) { a0[g] = xg[g]; a2[g] = (f32x4){0.f,0.f,0.f,0.f}; }
        if (t > 0) {
#pragma unroll
            for (int kh = 0; kh < 4; ++kh) {
                const int off = l15*136 + kh*32 + lhi*8;
                half8 ah = *(const half8*)&hh_t[off];
                half8 as = *(const half8*)&hl_t[off];
#pragma unroll
                for (int g = 0; g < 4; ++g) {
                    a0[g] = MFMA16(ah, whhH[g][kh],  a0[g]);
                    a2[g] = MFMA16(ah, whhLs[g][kh], a2[g]);
                    a2[g] = MFMA16(as, whhH[g][kh],  a2[g]);
                }
            }
        }
        float hnew[4];
#pragma unroll
        for (int j = 0; j < 4; ++j) {
            const float pi = a0[0][j] + a2[0][j]*IV_LO;
            const float pf = a0[1][j] + a2[1][j]*IV_LO;
            const float pg = a0[2][j] + a2[2][j]*IV_LO;
            const float po = a0[3][j] + a2[3][j]*IV_LO;
            const float si = sigm_s(pi);
            const float sf = sigm_s(pf);
            const float tg = tanh_s(pg);
            const float so = sigm_s(po);
            const float cc = sf * c[j] + si * tg;
            c[j] = cc;
            hnew[j] = so * tanh_s(2.0f*L2E*cc);
        }
        __syncthreads();
#pragma unroll
        for (int j = 0; j < 4; ++j) {
            const int idx = (lhi*4 + j)*136 + 16*w + l15;
            const float v = hnew[j];
            const _Float16 hi = (_Float16)v;
            hh_t[idx] = hi;
            hl_t[idx] = (_Float16)((v - (float)hi) * SC_LO);
        }
        __syncthreads();
        // output head: out = h @ W_out^T + b_out, then activations
        if (tid < 320) {
            const int row = tid / 20, rem = tid % 20, j5 = rem / 4, q = rem % 4;
            float pacc = 0.0f;
#pragma unroll
            for (int e = 0; e < 32; ++e) {
                const int idx = row*136 + q*32 + e;
                pacc += ((float)hh_t[idx] + (float)hl_t[idx]*IV_LO) * wout[j5*132 + q*32 + e];
            }
            part[row][j5][q] = pacc;
        }
        __syncthreads();
        if (tid < 80) {
            const int row = tid / 5, j5 = tid % 5;
            float v = part[row][j5][0] + part[row][j5][1] + part[row][j5][2] + part[row][j5][3] + bout[j5];
            if (j5 == 2 || j5 == 3) v = fexp2(v * L2E);       // exp
            else if (j5 == 4)       v = tanh_s(2.0f*L2E*v);   // tanh
            outp[((size_t)(rb + row)*16 + t)*5 + j5] = v;     // fp32 store
        }
    }
}

// ---------------------------------------------------------------------------
extern "C" void kernel_launch(void* const* d_in, const int* in_sizes, int n_in,
                              void* d_out, int out_size, void* d_ws, size_t ws_size,
                              hipStream_t stream) {
    const float* hist  = (const float*)d_in[0];   // [16][4096][2]
    const float* nbrs  = (const float*)d_in[1];   // [16][131072][2]
    const float* W_inp = (const float*)d_in[2];
    const float* b_inp = (const float*)d_in[3];
    const float* Wih   = (const float*)d_in[4];
    const float* Whh   = (const float*)d_in[5];
    const float* bih   = (const float*)d_in[6];
    const float* bhh   = (const float*)d_in[7];
    const float* W_dym = (const float*)d_in[8];
    const float* b_dym = (const float*)d_in[9];
    const float* W_sp  = (const float*)d_in[10];
    const float* b_sp  = (const float*)d_in[11];
    const float* dWih  = (const float*)d_in[12];
    const float* dWhh  = (const float*)d_in[13];
    const float* dbih  = (const float*)d_in[14];
    const float* dbhh  = (const float*)d_in[15];
    const float* W_out = (const float*)d_in[16];
    const float* b_out = (const float*)d_in[17];
    const void* mask   = (const void*)d_in[18];   // dtype auto-detected on device

    char* ws = (char*)d_ws;
    float* nh32        = (float*)(ws);                    // 131072*64*4 = 33554432
    float* hh32        = (float*)(ws + 33554432);         // 4096*64*4   = 1048576
    _Float16* WspT16   = (_Float16*)(ws + 34603008);      // 169*64*64*2 = 1384448
    unsigned char* pos = (unsigned char*)(ws + 35987456); // 4096*32     = 131072
    float* enc32       = (float*)(ws + 36118528);         // 4096*96*4   = 1572864

    mega_enc_kernel<<<5840, 256, 0, stream>>>(hist, nbrs, W_inp, b_inp, Wih, Whh, bih, bhh,
                                              W_sp, mask, hh32, nh32, WspT16, pos);
    social_kernel<<<4096, 256, 0, stream>>>(nh32, hh32, WspT16, b_sp, W_dym, b_dym, pos, enc32);
    decoder_kernel<<<256, 512, 0, stream>>>(enc32, dWih, dWhh, dbih, dbhh, W_out, b_out,
                                            (float*)d_out);
}